// Round 4
// baseline (995.359 us; speedup 1.0000x reference)
//
#include <hip/hip_runtime.h>

#define KCODES 512
#define DDIM   64
#define NROWS  131072

typedef short bf16x8 __attribute__((ext_vector_type(8)));
typedef float f32x4  __attribute__((ext_vector_type(4)));
typedef int   i32x4  __attribute__((ext_vector_type(4)));

__device__ __forceinline__ unsigned f32_to_bf16_rne(float x) {
    unsigned u = __float_as_uint(x);
    return (u + 0x7fffu + ((u >> 16) & 1u)) >> 16;   // RNE to bf16 (data is finite/normal)
}

// ---------------- K1a: e_norm[k] + emax scalar ----------------
__global__ __launch_bounds__(512) void k1_enorm(const float* __restrict__ emb,
                                                float* __restrict__ en, float* __restrict__ emaxp) {
    __shared__ float red[512];
    int k = threadIdx.x;
    float s = 0.f;
#pragma unroll
    for (int d = 0; d < DDIM; ++d) { float e = emb[k * DDIM + d]; s = fmaf(e, e, s); }
    en[k] = s;
    red[k] = s;
    __syncthreads();
    for (int st = 256; st > 0; st >>= 1) {
        if (k < st) red[k] = fmaxf(red[k], red[k + st]);
        __syncthreads();
    }
    if (k == 0) emaxp[0] = sqrtf(red[0]) * 1.0001f;   // upper bound on max ||e_k||
}

// ---------------- K1b: codebook -> bf16 MFMA B-fragments ----------------
// frag chunk (kt,c,lane): lane holds e[kt*16+(lane&15)][c*32+(lane>>4)*8 + j], j=0..7
__global__ __launch_bounds__(128) void k1_efrag(const float* __restrict__ emb,
                                                i32x4* __restrict__ efh) {
    int kt = blockIdx.x;
    int t = threadIdx.x;
    int c = t >> 6, lane = t & 63;
    int krow = kt * 16 + (lane & 15);
    int d0 = c * 32 + ((lane >> 4) * 8);
    const float* src = emb + krow * DDIM + d0;
    unsigned h[8];
#pragma unroll
    for (int j = 0; j < 8; ++j) h[j] = f32_to_bf16_rne(src[j]);
    i32x4 w;
#pragma unroll
    for (int i = 0; i < 4; ++i) w[i] = (int)(h[2 * i] | (h[2 * i + 1] << 16));
    efh[(kt * 2 + c) * 64 + lane] = w;
}

// ---------------- K2: z -> bf16 A-fragments + z_norm ----------------
// block = 64 rows; z layout [B,D,H,W]: (b,d,hw) at b*D*4096 + d*4096 + hw
__global__ __launch_bounds__(256) void k2_zprep(const float* __restrict__ z,
                                                i32x4* __restrict__ zfh, float* __restrict__ zn) {
    __shared__ float zt[64 * 65];   // [d][row] padded
    int t = threadIdx.x, blk = blockIdx.x;
    int n0 = blk * 64;
    int b = n0 >> 12, hw0 = n0 & 4095;
    const float* zb = z + (size_t)b * (DDIM * 4096) + hw0;
    int l = t & 63, dq = t >> 6;
#pragma unroll
    for (int i = 0; i < 16; ++i) {
        int d = dq * 16 + i;
        zt[d * 65 + l] = zb[(size_t)d * 4096 + l];   // 256B coalesced per (wave,d)
    }
    __syncthreads();
    if (t < 64) {   // z_norm, sequential-d fmaf chain (round-1 semantics)
        float s = 0.f;
#pragma unroll
        for (int d = 0; d < DDIM; ++d) { float v = zt[d * 65 + t]; s = fmaf(v, v, s); }
        zn[n0 + t] = s;
    }
#pragma unroll
    for (int q = 0; q < 2; ++q) {
        int chunk = q * 256 + t;            // (tl, c, lane)
        int tl = chunk >> 7;
        int c = (chunk >> 6) & 1;
        int lane = chunk & 63;
        int rowl = tl * 16 + (lane & 15);
        int d0 = c * 32 + ((lane >> 4) * 8);
        unsigned h[8];
#pragma unroll
        for (int j = 0; j < 8; ++j) h[j] = f32_to_bf16_rne(zt[(d0 + j) * 65 + rowl]);
        i32x4 w;
#pragma unroll
        for (int i = 0; i < 4; ++i) w[i] = (int)(h[2 * i] | (h[2 * i + 1] << 16));
        zfh[((blk * 4 + tl) * 2 + c) * 64 + lane] = w;
    }
}

// ---------------- K3: MFMA approx distances + top-2 + ambiguity flag ----------------
// block = 4 waves x 4 row-tiles = 256 rows; full codebook fragments staged in LDS (64KB)
__global__ __launch_bounds__(256, 2) void k3_mfma(
    const i32x4* __restrict__ zfh, const i32x4* __restrict__ efh,
    const float* __restrict__ en_g, const float* __restrict__ zn_g,
    const float* __restrict__ emaxp, int* __restrict__ out,
    unsigned long long* __restrict__ res, int* __restrict__ list, int* __restrict__ cnt) {

    __shared__ i32x4 ef[4096];      // 64 KB: (kt,c,lane)
    __shared__ float zn_l[256];
    __shared__ float en_l[KCODES];

    int t = threadIdx.x, blk = blockIdx.x;
#pragma unroll
    for (int j = 0; j < 16; ++j) ef[t + j * 256] = efh[t + j * 256];
    zn_l[t] = zn_g[blk * 256 + t];
    en_l[t] = en_g[t];
    en_l[t + 256] = en_g[t + 256];
    __syncthreads();

    int w = t >> 6, lane = t & 63;
    int klane = lane & 15;
    float emax = emaxp[0];

    const bf16x8* zfb = (const bf16x8*)zfh;
    bf16x8 zf[4][2];
#pragma unroll
    for (int tl = 0; tl < 4; ++tl)
#pragma unroll
        for (int c = 0; c < 2; ++c) {
            int tile = blk * 16 + w * 4 + tl;
            zf[tl][c] = zfb[(tile * 2 + c) * 64 + lane];
        }
    f32x4 zn4[4];
#pragma unroll
    for (int tl = 0; tl < 4; ++tl)
        zn4[tl] = *(const f32x4*)&zn_l[(w * 4 + tl) * 16 + ((lane >> 4) * 4)];

    float m1[4][4], m2[4][4];
    int i1[4][4];
#pragma unroll
    for (int tl = 0; tl < 4; ++tl)
#pragma unroll
        for (int r = 0; r < 4; ++r) { m1[tl][r] = 3.4e38f; m2[tl][r] = 3.4e38f; i1[tl][r] = 0; }

    f32x4 zero = {0.f, 0.f, 0.f, 0.f};
    for (int kt = 0; kt < 32; ++kt) {
        float enk = en_l[kt * 16 + klane];
        bf16x8 e0 = *(const bf16x8*)&ef[(kt * 2 + 0) * 64 + lane];
        bf16x8 e1 = *(const bf16x8*)&ef[(kt * 2 + 1) * 64 + lane];
        f32x4 acc[4];
#pragma unroll
        for (int tl = 0; tl < 4; ++tl)
            acc[tl] = __builtin_amdgcn_mfma_f32_16x16x32_bf16(zf[tl][0], e0, zero, 0, 0, 0);
#pragma unroll
        for (int tl = 0; tl < 4; ++tl)
            acc[tl] = __builtin_amdgcn_mfma_f32_16x16x32_bf16(zf[tl][1], e1, acc[tl], 0, 0, 0);
        int k = kt * 16 + klane;
#pragma unroll
        for (int tl = 0; tl < 4; ++tl)
#pragma unroll
            for (int r = 0; r < 4; ++r) {
                float s1 = zn4[tl][r] + enk;
                float d = fmaf(-2.f, acc[tl][r], s1);   // same final rounding as numpy's s1-2p
                float o1 = m1[tl][r];
                i1[tl][r] = (d < o1) ? k : i1[tl][r];
                m2[tl][r] = fminf(m2[tl][r], fmaxf(o1, d));
                m1[tl][r] = fminf(o1, d);
            }
    }

    // reduce across the 16 code-lanes (same rows): xor 1,2,4,8
#pragma unroll
    for (int s = 1; s <= 8; s <<= 1) {
#pragma unroll
        for (int tl = 0; tl < 4; ++tl)
#pragma unroll
            for (int r = 0; r < 4; ++r) {
                float om1 = __shfl_xor(m1[tl][r], s);
                int oi1 = __shfl_xor(i1[tl][r], s);
                float om2 = __shfl_xor(m2[tl][r], s);
                float hi = fmaxf(m1[tl][r], om1);
                m2[tl][r] = fminf(fminf(m2[tl][r], om2), hi);
                i1[tl][r] = (om1 < m1[tl][r]) ? oi1 : i1[tl][r];
                m1[tl][r] = fminf(m1[tl][r], om1);
            }
    }

    if (klane == 0) {
        int g = lane >> 4;
#pragma unroll
        for (int tl = 0; tl < 4; ++tl) {
            int rowbase = (blk * 16 + w * 4 + tl) * 16 + g * 4;
            i32x4 idx4;
#pragma unroll
            for (int r = 0; r < 4; ++r) idx4[r] = i1[tl][r];
            *(i32x4*)(out + rowbase) = idx4;     // approx winner for all rows
#pragma unroll
            for (int r = 0; r < 4; ++r) {
                float zz = zn4[tl][r];
                // guaranteed err bound: 2*2^-8*||z||*||e||max (x2 margin) + ~17 ulp chain noise
                float W = fmaf(zz, 2.5e-6f, 0.018f * sqrtf(zz) * emax);
                if (m2[tl][r] - m1[tl][r] <= W) {
                    int row = rowbase + r;
                    int pos = atomicAdd(cnt, 1);
                    list[pos] = row;
                    res[row] = 0xFFFFFFFFFFFFFFFFull;
                }
            }
        }
    }
}

// ---------------- K4: exact fp32 refine of flagged rows ----------------
// 4 threads per listed row (128 codes each); u64 atomicMin of (dist_bits<<32|k)
__global__ __launch_bounds__(256) void k4_refine(
    const float* __restrict__ z, const float* __restrict__ emb,
    const float* __restrict__ en, const float* __restrict__ zn_g,
    const int* __restrict__ list, const int* __restrict__ cnt,
    unsigned long long* __restrict__ res) {
    int t = threadIdx.x;
    int li = blockIdx.x * 64 + (t >> 2);
    if (li >= cnt[0]) return;
    int row = list[li];
    int kq = t & 3;
    int b = row >> 12, hw = row & 4095;
    const float* zp = z + (size_t)b * (DDIM * 4096) + hw;
    float zr[DDIM];
#pragma unroll
    for (int d = 0; d < DDIM; ++d) zr[d] = zp[(size_t)d * 4096];
    float zn = zn_g[row];
    float best = 3.4e38f;
    int bi = 0;
    for (int k0 = kq * 128; k0 < kq * 128 + 128; k0 += 8) {
        float acc[8];
#pragma unroll
        for (int kk = 0; kk < 8; ++kk) acc[kk] = 0.f;
        const float* e0 = emb + k0 * DDIM;
#pragma unroll
        for (int d = 0; d < DDIM; ++d) {
            float zd = zr[d];
#pragma unroll
            for (int kk = 0; kk < 8; ++kk) acc[kk] = fmaf(e0[kk * DDIM + d], zd, acc[kk]);
        }
#pragma unroll
        for (int kk = 0; kk < 8; ++kk) {
            float dist = fmaf(-2.f, acc[kk], zn + en[k0 + kk]);
            if (dist < best) { best = dist; bi = k0 + kk; }
        }
    }
    // dist > 0 always here (|z-e|^2 ~ 64); bits order == float order; low32 k => first-occurrence ties
    unsigned long long key = ((unsigned long long)__float_as_uint(best) << 32) | (unsigned)bi;
    atomicMin(res + row, key);
}

__global__ __launch_bounds__(256) void k5_fix(const int* __restrict__ list,
                                              const int* __restrict__ cnt,
                                              const unsigned long long* __restrict__ res,
                                              int* __restrict__ out) {
    int i = blockIdx.x * 256 + threadIdx.x;
    if (i >= cnt[0]) return;
    int row = list[i];
    out[row] = (int)(res[row] & 0xFFFFFFFFull);
}

// ---------------- fallback (round-1, known-good) ----------------
__global__ void fb_enorm(const float* __restrict__ emb, float* __restrict__ en) {
    int k = blockIdx.x * blockDim.x + threadIdx.x;
    if (k < KCODES) {
        float s = 0.f;
#pragma unroll
        for (int d = 0; d < DDIM; ++d) { float e = emb[k * DDIM + d]; s = fmaf(e, e, s); }
        en[k] = s;
    }
}
__global__ __launch_bounds__(256) void fb_argmin(const float* __restrict__ z,
                                                 const float* __restrict__ emb,
                                                 const float* __restrict__ en,
                                                 int* __restrict__ out, int nrows) {
    int n = blockIdx.x * blockDim.x + threadIdx.x;
    if (n >= nrows) return;
    int b = n >> 12, hw = n & 4095;
    const float* zp = z + (size_t)b * (DDIM * 4096) + hw;
    float zr[DDIM];
#pragma unroll
    for (int d = 0; d < DDIM; ++d) zr[d] = zp[(size_t)d * 4096];
    float zn = 0.f;
#pragma unroll
    for (int d = 0; d < DDIM; ++d) zn = fmaf(zr[d], zr[d], zn);
    float best = 3.4e38f; int bi = 0;
    for (int k0 = 0; k0 < KCODES; k0 += 8) {
        float acc[8];
#pragma unroll
        for (int kk = 0; kk < 8; ++kk) acc[kk] = 0.f;
        const float* e0 = emb + k0 * DDIM;
#pragma unroll
        for (int d = 0; d < DDIM; ++d) {
            float zd = zr[d];
#pragma unroll
            for (int kk = 0; kk < 8; ++kk) acc[kk] = fmaf(e0[kk * DDIM + d], zd, acc[kk]);
        }
#pragma unroll
        for (int kk = 0; kk < 8; ++kk) {
            float dist = fmaf(-2.f, acc[kk], zn + en[k0 + kk]);
            if (dist < best) { best = dist; bi = k0 + kk; }
        }
    }
    out[n] = bi;
}

extern "C" void kernel_launch(void* const* d_in, const int* in_sizes, int n_in,
                              void* d_out, int out_size, void* d_ws, size_t ws_size,
                              hipStream_t stream) {
    const float* z   = (const float*)d_in[0];   // [32,64,64,64] fp32
    const float* emb = (const float*)d_in[1];   // [512,64] fp32
    int* out = (int*)d_out;                     // 131072 int32

    // ws layout
    const size_t SZ_ZFH  = (size_t)NROWS / 16 * 2 * 64 * 16;  // 16 MB
    const size_t SZ_EFH  = 32 * 2 * 64 * 16;                  // 64 KB
    const size_t SZ_EN   = KCODES * 4;
    const size_t SZ_ZN   = (size_t)NROWS * 4;
    const size_t SZ_EMAX = 64;
    const size_t SZ_RES  = (size_t)NROWS * 8;
    const size_t SZ_LIST = (size_t)NROWS * 4;
    const size_t SZ_CNT  = 64;
    const size_t NEED = SZ_ZFH + SZ_EFH + SZ_EN + SZ_ZN + SZ_EMAX + SZ_RES + SZ_LIST + SZ_CNT;

    if (ws_size < NEED) {   // safety net: round-1 path (slow but correct)
        float* en = (float*)d_ws;
        fb_enorm<<<2, 256, 0, stream>>>(emb, en);
        fb_argmin<<<NROWS / 256, 256, 0, stream>>>(z, emb, en, out, NROWS);
        return;
    }

    char* p = (char*)d_ws;
    i32x4* zfh = (i32x4*)p;                 p += SZ_ZFH;
    i32x4* efh = (i32x4*)p;                 p += SZ_EFH;
    float* en  = (float*)p;                 p += SZ_EN;
    float* zn  = (float*)p;                 p += SZ_ZN;
    float* emaxp = (float*)p;               p += SZ_EMAX;
    unsigned long long* res = (unsigned long long*)p; p += SZ_RES;
    int* list = (int*)p;                    p += SZ_LIST;
    int* cnt  = (int*)p;

    k1_enorm<<<1, 512, 0, stream>>>(emb, en, emaxp);
    k1_efrag<<<32, 128, 0, stream>>>(emb, efh);
    k2_zprep<<<NROWS / 64, 256, 0, stream>>>(z, zfh, zn);
    hipMemsetAsync(cnt, 0, 4, stream);
    k3_mfma<<<NROWS / 256, 256, 0, stream>>>(zfh, efh, en, zn, emaxp, out, res, list, cnt);
    k4_refine<<<NROWS / 64, 256, 0, stream>>>(z, emb, en, zn, list, cnt, res);
    k5_fix<<<NROWS / 256, 256, 0, stream>>>(list, cnt, res, out);
}

// Round 5
// 139.150 us; speedup vs baseline: 7.1531x; 7.1531x over previous
//
#include <hip/hip_runtime.h>

#define KCODES 512
#define DDIM   64
#define NROWS  131072
#define HALFROWS (NROWS / 2)

typedef short bf16x8 __attribute__((ext_vector_type(8)));
typedef float f32x4  __attribute__((ext_vector_type(4)));
typedef int   i32x4  __attribute__((ext_vector_type(4)));

__device__ __forceinline__ unsigned f32_to_bf16_rne(float x) {
    unsigned u = __float_as_uint(x);
    return (u + 0x7fffu + ((u >> 16) & 1u)) >> 16;   // RNE (finite/normal data)
}

// ---------------- K1a: e_norm[k] + emax ----------------
__global__ __launch_bounds__(512) void k1_enorm(const float* __restrict__ emb,
                                                float* __restrict__ en, float* __restrict__ emaxp) {
    __shared__ float red[512];
    int k = threadIdx.x;
    float s = 0.f;
#pragma unroll
    for (int d = 0; d < DDIM; ++d) { float e = emb[k * DDIM + d]; s = fmaf(e, e, s); }
    en[k] = s;
    red[k] = s;
    __syncthreads();
    for (int st = 256; st > 0; st >>= 1) {
        if (k < st) red[k] = fmaxf(red[k], red[k + st]);
        __syncthreads();
    }
    if (k == 0) emaxp[0] = sqrtf(red[0]) * 1.0001f;
}

// ---------------- K1b: codebook -> split-bf16 B-fragments (hi, lo) ----------------
// chunk (kt,c,lane): lane holds e[kt*16+(lane&15)][c*32+(lane>>4)*8 + j], j=0..7
__global__ __launch_bounds__(128) void k1_efrag(const float* __restrict__ emb,
                                                i32x4* __restrict__ efA, i32x4* __restrict__ efB) {
    int kt = blockIdx.x, t = threadIdx.x;
    int c = t >> 6, lane = t & 63;
    int krow = kt * 16 + (lane & 15);
    int d0 = c * 32 + ((lane >> 4) * 8);
    const float* src = emb + krow * DDIM + d0;
    unsigned hh[8], hl[8];
#pragma unroll
    for (int j = 0; j < 8; ++j) {
        float x = src[j];
        unsigned h = f32_to_bf16_rne(x);
        float hf = __uint_as_float(h << 16);
        hh[j] = h;
        hl[j] = f32_to_bf16_rne(x - hf);
    }
    i32x4 wh, wl;
#pragma unroll
    for (int i = 0; i < 4; ++i) {
        wh[i] = (int)(hh[2 * i] | (hh[2 * i + 1] << 16));
        wl[i] = (int)(hl[2 * i] | (hl[2 * i + 1] << 16));
    }
    efA[(kt * 2 + c) * 64 + lane] = wh;
    efB[(kt * 2 + c) * 64 + lane] = wl;
}

// ---------------- K2: z -> split-bf16 A-fragments + z_norm (per half) ----------------
__global__ __launch_bounds__(256) void k2_zprep(const float* __restrict__ z,
                                                i32x4* __restrict__ zfA, i32x4* __restrict__ zfB,
                                                float* __restrict__ zn, int row0) {
    __shared__ float zt[64 * 65];   // [d][row] padded
    int t = threadIdx.x, blk = blockIdx.x;
    int n0 = row0 + blk * 64;
    int b = n0 >> 12, hw0 = n0 & 4095;
    const float* zb = z + (size_t)b * (DDIM * 4096) + hw0;
    int l = t & 63, dq = t >> 6;
#pragma unroll
    for (int i = 0; i < 16; ++i) {
        int d = dq * 16 + i;
        zt[d * 65 + l] = zb[(size_t)d * 4096 + l];
    }
    __syncthreads();
    if (t < 64) {   // z_norm: sequential-d fmaf chain (round-1 semantics)
        float s = 0.f;
#pragma unroll
        for (int d = 0; d < DDIM; ++d) { float v = zt[d * 65 + t]; s = fmaf(v, v, s); }
        zn[n0 + t] = s;
    }
#pragma unroll
    for (int q = 0; q < 2; ++q) {
        int chunk = q * 256 + t;            // (tl, c, lane)
        int tl = chunk >> 7;
        int c = (chunk >> 6) & 1;
        int lane = chunk & 63;
        int rowl = tl * 16 + (lane & 15);
        int d0 = c * 32 + ((lane >> 4) * 8);
        unsigned hh[8], hl[8];
#pragma unroll
        for (int j = 0; j < 8; ++j) {
            float x = zt[(d0 + j) * 65 + rowl];
            unsigned h = f32_to_bf16_rne(x);
            float hf = __uint_as_float(h << 16);
            hh[j] = h;
            hl[j] = f32_to_bf16_rne(x - hf);
        }
        i32x4 wh, wl;
#pragma unroll
        for (int i = 0; i < 4; ++i) {
            wh[i] = (int)(hh[2 * i] | (hh[2 * i + 1] << 16));
            wl[i] = (int)(hl[2 * i] | (hl[2 * i + 1] << 16));
        }
        int idx = ((blk * 4 + tl) * 2 + c) * 64 + lane;
        zfA[idx] = wh;
        zfB[idx] = wl;
    }
}

// ---------------- K3: split-bf16 MFMA distances + top-2 + flag (per half) ----------------
// block = 4 waves x 4 row-tiles = 256 rows; e-frags read direct from global (L2-resident)
__global__ __launch_bounds__(256, 2) void k3_mfma(
    const i32x4* __restrict__ zfA, const i32x4* __restrict__ zfB,
    const i32x4* __restrict__ efA, const i32x4* __restrict__ efB,
    const float* __restrict__ en_g, const float* __restrict__ zn_g,
    const float* __restrict__ emaxp, int* __restrict__ out,
    int* __restrict__ list, int* __restrict__ cnt, int row0) {

    __shared__ float zn_l[256];
    __shared__ float en_l[KCODES];

    int t = threadIdx.x, blk = blockIdx.x;
    zn_l[t] = zn_g[row0 + blk * 256 + t];
    en_l[t] = en_g[t];
    en_l[t + 256] = en_g[t + 256];
    __syncthreads();

    int w = t >> 6, lane = t & 63, klane = lane & 15;
    float emax = emaxp[0];

    const bf16x8* zA = (const bf16x8*)zfA;
    const bf16x8* zB = (const bf16x8*)zfB;
    bf16x8 zh[4][2], zl[4][2];
#pragma unroll
    for (int tl = 0; tl < 4; ++tl)
#pragma unroll
        for (int c = 0; c < 2; ++c) {
            int idx = ((blk * 16 + w * 4 + tl) * 2 + c) * 64 + lane;
            zh[tl][c] = zA[idx];
            zl[tl][c] = zB[idx];
        }
    f32x4 zn4[4];
#pragma unroll
    for (int tl = 0; tl < 4; ++tl)
        zn4[tl] = *(const f32x4*)&zn_l[(w * 4 + tl) * 16 + ((lane >> 4) * 4)];

    float m1[4][4], m2[4][4];
    int i1[4][4];
#pragma unroll
    for (int tl = 0; tl < 4; ++tl)
#pragma unroll
        for (int r = 0; r < 4; ++r) { m1[tl][r] = 3.4e38f; m2[tl][r] = 3.4e38f; i1[tl][r] = 0; }

    const bf16x8* eA = (const bf16x8*)efA;
    const bf16x8* eB = (const bf16x8*)efB;
    f32x4 zero = {0.f, 0.f, 0.f, 0.f};
    for (int kt = 0; kt < 32; ++kt) {
        bf16x8 e0h = eA[(kt * 2 + 0) * 64 + lane];
        bf16x8 e1h = eA[(kt * 2 + 1) * 64 + lane];
        bf16x8 e0l = eB[(kt * 2 + 0) * 64 + lane];
        bf16x8 e1l = eB[(kt * 2 + 1) * 64 + lane];
        float enk = en_l[kt * 16 + klane];
        int k = kt * 16 + klane;
#pragma unroll
        for (int tl = 0; tl < 4; ++tl) {
            f32x4 acc = __builtin_amdgcn_mfma_f32_16x16x32_bf16(zh[tl][0], e0h, zero, 0, 0, 0);
            acc = __builtin_amdgcn_mfma_f32_16x16x32_bf16(zh[tl][1], e1h, acc, 0, 0, 0);
            acc = __builtin_amdgcn_mfma_f32_16x16x32_bf16(zh[tl][0], e0l, acc, 0, 0, 0);
            acc = __builtin_amdgcn_mfma_f32_16x16x32_bf16(zh[tl][1], e1l, acc, 0, 0, 0);
            acc = __builtin_amdgcn_mfma_f32_16x16x32_bf16(zl[tl][0], e0h, acc, 0, 0, 0);
            acc = __builtin_amdgcn_mfma_f32_16x16x32_bf16(zl[tl][1], e1h, acc, 0, 0, 0);
#pragma unroll
            for (int r = 0; r < 4; ++r) {
                float s1 = zn4[tl][r] + enk;
                float d = fmaf(-2.f, acc[r], s1);   // same rounding as refine path
                float o1 = m1[tl][r];
                i1[tl][r] = (d < o1) ? k : i1[tl][r];
                m2[tl][r] = fminf(m2[tl][r], fmaxf(o1, d));
                m1[tl][r] = fminf(o1, d);
            }
        }
    }

    // reduce across the 16 code-lanes (same rows): xor 1,2,4,8
#pragma unroll
    for (int s = 1; s <= 8; s <<= 1) {
#pragma unroll
        for (int tl = 0; tl < 4; ++tl)
#pragma unroll
            for (int r = 0; r < 4; ++r) {
                float om1 = __shfl_xor(m1[tl][r], s);
                int oi1 = __shfl_xor(i1[tl][r], s);
                float om2 = __shfl_xor(m2[tl][r], s);
                float hi = fmaxf(m1[tl][r], om1);
                m2[tl][r] = fminf(fminf(m2[tl][r], om2), hi);
                i1[tl][r] = (om1 < m1[tl][r]) ? oi1 : i1[tl][r];
                m1[tl][r] = fminf(m1[tl][r], om1);
            }
    }

    if (klane == 0) {
        int g = lane >> 4;
#pragma unroll
        for (int tl = 0; tl < 4; ++tl) {
            int rowbase = row0 + (blk * 16 + w * 4 + tl) * 16 + g * 4;
            i32x4 idx4;
#pragma unroll
            for (int r = 0; r < 4; ++r) idx4[r] = i1[tl][r];
            *(i32x4*)(out + rowbase) = idx4;
#pragma unroll
            for (int r = 0; r < 4; ++r) {
                float zz = zn4[tl][r];
                // |split-mfma dist - seq-fp32 dist| bound (x~3 margin):
                float W = fmaf(sqrtf(zz) * emax, 1.0e-4f, zz * 1.0e-6f);
                if (m2[tl][r] - m1[tl][r] <= W) {
                    int pos = atomicAdd(cnt, 1);
                    list[pos] = rowbase + r;
                }
            }
        }
    }
}

// ---------------- K4: exact fp32 refine, one wave per listed row ----------------
__global__ __launch_bounds__(256) void k4_refine(
    const float* __restrict__ z, const float* __restrict__ emb,
    const float* __restrict__ en, const float* __restrict__ zn_g,
    const int* __restrict__ list, const int* __restrict__ cnt,
    int* __restrict__ out) {
    __shared__ float zrow[4][64];
    int t = threadIdx.x;
    int w = t >> 6, lane = t & 63;
    int nlist = cnt[0];
    for (int li = blockIdx.x * 4 + w; li < nlist; li += gridDim.x * 4) {
        int row = list[li];
        int b = row >> 12, hw = row & 4095;
        const float* zp = z + (size_t)b * (DDIM * 4096) + hw;
        zrow[w][lane] = zp[(size_t)lane * 4096];   // in-wave LDS ordering: program order
        float zn = zn_g[row];
        float best = 3.4e38f;
        int bi = 0;
#pragma unroll 1
        for (int kk = 0; kk < 8; ++kk) {
            int k = lane * 8 + kk;
            const float* e0 = emb + k * DDIM;
            float acc = 0.f;
#pragma unroll
            for (int d = 0; d < DDIM; ++d) acc = fmaf(e0[d], zrow[w][d], acc);
            float dist = fmaf(-2.f, acc, zn + en[k]);
            if (dist < best) { best = dist; bi = k; }   // ascending k: first-occurrence
        }
        // dist > 0 here; float-bit order == value order; low word = k (min key -> min k on ties)
        unsigned long long key =
            ((unsigned long long)__float_as_uint(best) << 32) | (unsigned)bi;
#pragma unroll
        for (int s = 32; s; s >>= 1) {
            unsigned long long o = __shfl_xor(key, s);
            key = (o < key) ? o : key;
        }
        if (lane == 0) out[row] = (int)(key & 0xFFFFFFFFull);
    }
}

// ---------------- fallback (round-1, known-good) ----------------
__global__ void fb_enorm(const float* __restrict__ emb, float* __restrict__ en) {
    int k = blockIdx.x * blockDim.x + threadIdx.x;
    if (k < KCODES) {
        float s = 0.f;
#pragma unroll
        for (int d = 0; d < DDIM; ++d) { float e = emb[k * DDIM + d]; s = fmaf(e, e, s); }
        en[k] = s;
    }
}
__global__ __launch_bounds__(256) void fb_argmin(const float* __restrict__ z,
                                                 const float* __restrict__ emb,
                                                 const float* __restrict__ en,
                                                 int* __restrict__ out, int nrows) {
    int n = blockIdx.x * blockDim.x + threadIdx.x;
    if (n >= nrows) return;
    int b = n >> 12, hw = n & 4095;
    const float* zp = z + (size_t)b * (DDIM * 4096) + hw;
    float zr[DDIM];
#pragma unroll
    for (int d = 0; d < DDIM; ++d) zr[d] = zp[(size_t)d * 4096];
    float zn = 0.f;
#pragma unroll
    for (int d = 0; d < DDIM; ++d) zn = fmaf(zr[d], zr[d], zn);
    float best = 3.4e38f; int bi = 0;
    for (int k0 = 0; k0 < KCODES; k0 += 8) {
        float acc[8];
#pragma unroll
        for (int kk = 0; kk < 8; ++kk) acc[kk] = 0.f;
        const float* e0 = emb + k0 * DDIM;
#pragma unroll
        for (int d = 0; d < DDIM; ++d) {
            float zd = zr[d];
#pragma unroll
            for (int kk = 0; kk < 8; ++kk) acc[kk] = fmaf(e0[kk * DDIM + d], zd, acc[kk]);
        }
#pragma unroll
        for (int kk = 0; kk < 8; ++kk) {
            float dist = fmaf(-2.f, acc[kk], zn + en[k0 + kk]);
            if (dist < best) { best = dist; bi = k0 + kk; }
        }
    }
    out[n] = bi;
}

extern "C" void kernel_launch(void* const* d_in, const int* in_sizes, int n_in,
                              void* d_out, int out_size, void* d_ws, size_t ws_size,
                              hipStream_t stream) {
    const float* z   = (const float*)d_in[0];   // [32,64,64,64] fp32
    const float* emb = (const float*)d_in[1];   // [512,64] fp32
    int* out = (int*)d_out;                     // 131072 int32

    const size_t SZ_ZF   = (size_t)(HALFROWS / 16) * 2 * 64 * 16;  // 8 MB per split buffer
    const size_t SZ_EF   = 32 * 2 * 64 * 16;                        // 64 KB
    const size_t SZ_EN   = KCODES * 4;
    const size_t SZ_ZN   = (size_t)NROWS * 4;
    const size_t SZ_EMAX = 64;
    const size_t SZ_LIST = (size_t)NROWS * 4;
    const size_t SZ_CNT  = 64;
    const size_t NEED = 2 * SZ_ZF + 2 * SZ_EF + SZ_EN + SZ_ZN + SZ_EMAX + SZ_LIST + SZ_CNT;

    if (ws_size < NEED) {   // safety net: round-1 path
        float* en = (float*)d_ws;
        fb_enorm<<<2, 256, 0, stream>>>(emb, en);
        fb_argmin<<<NROWS / 256, 256, 0, stream>>>(z, emb, en, out, NROWS);
        return;
    }

    char* p = (char*)d_ws;
    i32x4* zfA = (i32x4*)p;   p += SZ_ZF;
    i32x4* zfB = (i32x4*)p;   p += SZ_ZF;
    i32x4* efA = (i32x4*)p;   p += SZ_EF;
    i32x4* efB = (i32x4*)p;   p += SZ_EF;
    float* en  = (float*)p;   p += SZ_EN;
    float* zn  = (float*)p;   p += SZ_ZN;
    float* emaxp = (float*)p; p += SZ_EMAX;
    int* list = (int*)p;      p += SZ_LIST;
    int* cnt  = (int*)p;

    k1_enorm<<<1, 512, 0, stream>>>(emb, en, emaxp);
    k1_efrag<<<32, 128, 0, stream>>>(emb, efA, efB);
    hipMemsetAsync(cnt, 0, 4, stream);

    // half 0
    k2_zprep<<<HALFROWS / 64, 256, 0, stream>>>(z, zfA, zfB, zn, 0);
    k3_mfma<<<HALFROWS / 256, 256, 0, stream>>>(zfA, zfB, efA, efB, en, zn, emaxp,
                                                out, list, cnt, 0);
    // half 1 (reuse zf buffers; stream-ordered)
    k2_zprep<<<HALFROWS / 64, 256, 0, stream>>>(z, zfA, zfB, zn, HALFROWS);
    k3_mfma<<<HALFROWS / 256, 256, 0, stream>>>(zfA, zfB, efA, efB, en, zn, emaxp,
                                                out, list, cnt, HALFROWS);

    k4_refine<<<512, 256, 0, stream>>>(z, emb, en, zn, list, cnt, out);
}

// Round 6
// 101.222 us; speedup vs baseline: 9.8334x; 1.3747x over previous
//
#include <hip/hip_runtime.h>

#define KCODES 512
#define DDIM   64
#define NROWS  131072

typedef short bf16x8 __attribute__((ext_vector_type(8)));
typedef float f32x4  __attribute__((ext_vector_type(4)));
typedef int   i32x4  __attribute__((ext_vector_type(4)));

union frag_cast { i32x4 i; bf16x8 h; };

__device__ __forceinline__ unsigned f32_to_bf16_rne(float x) {
    unsigned u = __float_as_uint(x);
    return (u + 0x7fffu + ((u >> 16) & 1u)) >> 16;   // RNE (finite/normal data)
}

// ---------------- K1a: e_norm[k] + emax ----------------
__global__ __launch_bounds__(512) void k1_enorm(const float* __restrict__ emb,
                                                float* __restrict__ en, float* __restrict__ emaxp) {
    __shared__ float red[512];
    int k = threadIdx.x;
    float s = 0.f;
#pragma unroll
    for (int d = 0; d < DDIM; ++d) { float e = emb[k * DDIM + d]; s = fmaf(e, e, s); }
    en[k] = s;
    red[k] = s;
    __syncthreads();
    for (int st = 256; st > 0; st >>= 1) {
        if (k < st) red[k] = fmaxf(red[k], red[k + st]);
        __syncthreads();
    }
    if (k == 0) emaxp[0] = sqrtf(red[0]) * 1.0001f;
}

// ---------------- K1b: codebook -> split-bf16 B-fragments (hi, lo) ----------------
// chunk (kt,c,lane): lane holds e[kt*16+(lane&15)][c*32+(lane>>4)*8 + j], j=0..7
__global__ __launch_bounds__(128) void k1_efrag(const float* __restrict__ emb,
                                                i32x4* __restrict__ efA, i32x4* __restrict__ efB) {
    int kt = blockIdx.x, t = threadIdx.x;
    int c = t >> 6, lane = t & 63;
    int krow = kt * 16 + (lane & 15);
    int d0 = c * 32 + ((lane >> 4) * 8);
    const float* src = emb + krow * DDIM + d0;
    unsigned hh[8], hl[8];
#pragma unroll
    for (int j = 0; j < 8; ++j) {
        float x = src[j];
        unsigned h = f32_to_bf16_rne(x);
        float hf = __uint_as_float(h << 16);
        hh[j] = h;
        hl[j] = f32_to_bf16_rne(x - hf);
    }
    i32x4 wh, wl;
#pragma unroll
    for (int i = 0; i < 4; ++i) {
        wh[i] = (int)(hh[2 * i] | (hh[2 * i + 1] << 16));
        wl[i] = (int)(hl[2 * i] | (hl[2 * i + 1] << 16));
    }
    efA[(kt * 2 + c) * 64 + lane] = wh;
    efB[(kt * 2 + c) * 64 + lane] = wl;
}

// ---------------- K3: fused z-load + split-bf16 conv + MFMA + top-2 + flag ----------
// block = 2 waves x 4 tiles = 128 rows; grid = 1024 (4 blocks/CU, 2 waves/SIMD)
__global__ __launch_bounds__(128, 2) void k3_fused(
    const float* __restrict__ z,
    const i32x4* __restrict__ efA_, const i32x4* __restrict__ efB_,
    const float* __restrict__ en_g, float* __restrict__ zn_g,
    const float* __restrict__ emaxp, int* __restrict__ out,
    int* __restrict__ list, int* __restrict__ cnt) {

    __shared__ float zt[DDIM * 133];   // [d][row], stride 133 (conflict-spread)
    __shared__ float zn_l[128];
    __shared__ float en_l[KCODES];

    const int t = threadIdx.x, blk = blockIdx.x;
    const int n0 = blk * 128;
    const int b = n0 >> 12, hw0 = n0 & 4095;   // 128 | 4096 -> one b per block

    // en -> LDS
#pragma unroll
    for (int q = 0; q < 4; ++q) en_l[t + q * 128] = en_g[t + q * 128];

    // z column load (coalesced per d) + z_norm (sequential-d fmaf = refine semantics)
    const float* zb = z + (size_t)b * (DDIM * 4096) + hw0 + t;
    float s = 0.f;
#pragma unroll
    for (int d = 0; d < DDIM; ++d) {
        float v = zb[(size_t)d * 4096];
        zt[d * 133 + t] = v;
        s = fmaf(v, v, s);
    }
    zn_l[t] = s;
    zn_g[n0 + t] = s;
    __syncthreads();

    const int w = t >> 6, lane = t & 63;
    const int klane = lane & 15, g = lane >> 4;
    const float emax = emaxp[0];

    // split-bf16 A-fragments for this wave's 4 row-tiles
    bf16x8 zh[4][2], zl[4][2];
#pragma unroll
    for (int tl = 0; tl < 4; ++tl) {
        int rowl = w * 64 + tl * 16 + klane;
#pragma unroll
        for (int c = 0; c < 2; ++c) {
            int d0 = c * 32 + g * 8;
            unsigned hh[8], hl[8];
#pragma unroll
            for (int j = 0; j < 8; ++j) {
                float x = zt[(d0 + j) * 133 + rowl];
                unsigned h = f32_to_bf16_rne(x);
                float hf = __uint_as_float(h << 16);
                hh[j] = h;
                hl[j] = f32_to_bf16_rne(x - hf);
            }
            frag_cast uh, ul;
#pragma unroll
            for (int i = 0; i < 4; ++i) {
                uh.i[i] = (int)(hh[2 * i] | (hh[2 * i + 1] << 16));
                ul.i[i] = (int)(hl[2 * i] | (hl[2 * i + 1] << 16));
            }
            zh[tl][c] = uh.h;
            zl[tl][c] = ul.h;
        }
    }

    f32x4 zn4[4];
#pragma unroll
    for (int tl = 0; tl < 4; ++tl)
        zn4[tl] = *(const f32x4*)&zn_l[w * 64 + tl * 16 + g * 4];

    float m1[4][4], m2[4][4];
    int i1[4][4];
#pragma unroll
    for (int tl = 0; tl < 4; ++tl)
#pragma unroll
        for (int r = 0; r < 4; ++r) { m1[tl][r] = 3.4e38f; m2[tl][r] = 3.4e38f; i1[tl][r] = 0; }

    const bf16x8* eA = (const bf16x8*)efA_;
    const bf16x8* eB = (const bf16x8*)efB_;
    f32x4 zero = {0.f, 0.f, 0.f, 0.f};

    // register-prefetched kt loop
    bf16x8 e0h = eA[lane], e1h = eA[64 + lane];
    bf16x8 e0l = eB[lane], e1l = eB[64 + lane];
#pragma unroll 2
    for (int kt = 0; kt < 32; ++kt) {
        int ktn = (kt + 1 < 32) ? kt + 1 : 31;      // clamped: no branch, in-bounds
        bf16x8 p0h = eA[ktn * 128 + lane];
        bf16x8 p1h = eA[ktn * 128 + 64 + lane];
        bf16x8 p0l = eB[ktn * 128 + lane];
        bf16x8 p1l = eB[ktn * 128 + 64 + lane];

        float enk = en_l[kt * 16 + klane];
        int k = kt * 16 + klane;
#pragma unroll
        for (int tl = 0; tl < 4; ++tl) {
            f32x4 acc = __builtin_amdgcn_mfma_f32_16x16x32_bf16(zh[tl][0], e0h, zero, 0, 0, 0);
            acc = __builtin_amdgcn_mfma_f32_16x16x32_bf16(zh[tl][1], e1h, acc, 0, 0, 0);
            acc = __builtin_amdgcn_mfma_f32_16x16x32_bf16(zh[tl][0], e0l, acc, 0, 0, 0);
            acc = __builtin_amdgcn_mfma_f32_16x16x32_bf16(zh[tl][1], e1l, acc, 0, 0, 0);
            acc = __builtin_amdgcn_mfma_f32_16x16x32_bf16(zl[tl][0], e0h, acc, 0, 0, 0);
            acc = __builtin_amdgcn_mfma_f32_16x16x32_bf16(zl[tl][1], e1h, acc, 0, 0, 0);
#pragma unroll
            for (int r = 0; r < 4; ++r) {
                float s1 = zn4[tl][r] + enk;
                float d = fmaf(-2.f, acc[r], s1);   // same rounding as refine path
                float o1 = m1[tl][r];
                i1[tl][r] = (d < o1) ? k : i1[tl][r];
                m2[tl][r] = fminf(m2[tl][r], fmaxf(o1, d));
                m1[tl][r] = fminf(o1, d);
            }
        }
        e0h = p0h; e1h = p1h; e0l = p0l; e1l = p1l;
    }

    // reduce across the 16 code-lanes: xor 1,2,4,8
#pragma unroll
    for (int sh = 1; sh <= 8; sh <<= 1) {
#pragma unroll
        for (int tl = 0; tl < 4; ++tl)
#pragma unroll
            for (int r = 0; r < 4; ++r) {
                float om1 = __shfl_xor(m1[tl][r], sh);
                int oi1 = __shfl_xor(i1[tl][r], sh);
                float om2 = __shfl_xor(m2[tl][r], sh);
                float hi = fmaxf(m1[tl][r], om1);
                m2[tl][r] = fminf(fminf(m2[tl][r], om2), hi);
                i1[tl][r] = (om1 < m1[tl][r]) ? oi1 : i1[tl][r];
                m1[tl][r] = fminf(m1[tl][r], om1);
            }
    }

    if (klane == 0) {
#pragma unroll
        for (int tl = 0; tl < 4; ++tl) {
            int rowbase = n0 + w * 64 + tl * 16 + g * 4;
            i32x4 idx4;
#pragma unroll
            for (int r = 0; r < 4; ++r) idx4[r] = i1[tl][r];
            *(i32x4*)(out + rowbase) = idx4;
#pragma unroll
            for (int r = 0; r < 4; ++r) {
                float zz = zn4[tl][r];
                // |split-mfma dist - seq-fp32 dist| bound (~3x margin), validated r5
                float W = fmaf(sqrtf(zz) * emax, 1.0e-4f, zz * 1.0e-6f);
                if (m2[tl][r] - m1[tl][r] <= W) {
                    int pos = atomicAdd(cnt, 1);
                    list[pos] = rowbase + r;
                }
            }
        }
    }
}

// ---------------- K4: exact fp32 refine, one wave per listed row ----------------
__global__ __launch_bounds__(256) void k4_refine(
    const float* __restrict__ z, const float* __restrict__ emb,
    const float* __restrict__ en, const float* __restrict__ zn_g,
    const int* __restrict__ list, const int* __restrict__ cnt,
    int* __restrict__ out) {
    __shared__ float zrow[4][64];
    int t = threadIdx.x;
    int w = t >> 6, lane = t & 63;
    int nlist = cnt[0];
    for (int li = blockIdx.x * 4 + w; li < nlist; li += gridDim.x * 4) {
        int row = list[li];
        int b = row >> 12, hw = row & 4095;
        const float* zp = z + (size_t)b * (DDIM * 4096) + hw;
        zrow[w][lane] = zp[(size_t)lane * 4096];
        float zn = zn_g[row];
        float best = 3.4e38f;
        int bi = 0;
#pragma unroll 1
        for (int kk = 0; kk < 8; ++kk) {
            int k = lane * 8 + kk;
            const float* e0 = emb + k * DDIM;
            float acc = 0.f;
#pragma unroll
            for (int d = 0; d < DDIM; ++d) acc = fmaf(e0[d], zrow[w][d], acc);
            float dist = fmaf(-2.f, acc, zn + en[k]);
            if (dist < best) { best = dist; bi = k; }   // ascending k: first-occurrence
        }
        unsigned long long key =
            ((unsigned long long)__float_as_uint(best) << 32) | (unsigned)bi;
#pragma unroll
        for (int sh = 32; sh; sh >>= 1) {
            unsigned long long o = __shfl_xor(key, sh);
            key = (o < key) ? o : key;
        }
        if (lane == 0) out[row] = (int)(key & 0xFFFFFFFFull);
    }
}

// ---------------- fallback (round-1, known-good) ----------------
__global__ void fb_enorm(const float* __restrict__ emb, float* __restrict__ en) {
    int k = blockIdx.x * blockDim.x + threadIdx.x;
    if (k < KCODES) {
        float s = 0.f;
#pragma unroll
        for (int d = 0; d < DDIM; ++d) { float e = emb[k * DDIM + d]; s = fmaf(e, e, s); }
        en[k] = s;
    }
}
__global__ __launch_bounds__(256) void fb_argmin(const float* __restrict__ z,
                                                 const float* __restrict__ emb,
                                                 const float* __restrict__ en,
                                                 int* __restrict__ out, int nrows) {
    int n = blockIdx.x * blockDim.x + threadIdx.x;
    if (n >= nrows) return;
    int b = n >> 12, hw = n & 4095;
    const float* zp = z + (size_t)b * (DDIM * 4096) + hw;
    float zr[DDIM];
#pragma unroll
    for (int d = 0; d < DDIM; ++d) zr[d] = zp[(size_t)d * 4096];
    float zn = 0.f;
#pragma unroll
    for (int d = 0; d < DDIM; ++d) zn = fmaf(zr[d], zr[d], zn);
    float best = 3.4e38f; int bi = 0;
    for (int k0 = 0; k0 < KCODES; k0 += 8) {
        float acc[8];
#pragma unroll
        for (int kk = 0; kk < 8; ++kk) acc[kk] = 0.f;
        const float* e0 = emb + k0 * DDIM;
#pragma unroll
        for (int d = 0; d < DDIM; ++d) {
            float zd = zr[d];
#pragma unroll
            for (int kk = 0; kk < 8; ++kk) acc[kk] = fmaf(e0[kk * DDIM + d], zd, acc[kk]);
        }
#pragma unroll
        for (int kk = 0; kk < 8; ++kk) {
            float dist = fmaf(-2.f, acc[kk], zn + en[k0 + kk]);
            if (dist < best) { best = dist; bi = k0 + kk; }
        }
    }
    out[n] = bi;
}

extern "C" void kernel_launch(void* const* d_in, const int* in_sizes, int n_in,
                              void* d_out, int out_size, void* d_ws, size_t ws_size,
                              hipStream_t stream) {
    const float* z   = (const float*)d_in[0];   // [32,64,64,64] fp32
    const float* emb = (const float*)d_in[1];   // [512,64] fp32
    int* out = (int*)d_out;                     // 131072 int32

    const size_t SZ_EF   = 32 * 2 * 64 * 16;    // 64 KB each
    const size_t SZ_EN   = KCODES * 4;
    const size_t SZ_ZN   = (size_t)NROWS * 4;
    const size_t SZ_EMAX = 64;
    const size_t SZ_LIST = (size_t)NROWS * 4;
    const size_t SZ_CNT  = 64;
    const size_t NEED = 2 * SZ_EF + SZ_EN + SZ_ZN + SZ_EMAX + SZ_LIST + SZ_CNT;  // ~1.2 MB

    if (ws_size < NEED) {   // safety net: round-1 path
        float* en = (float*)d_ws;
        fb_enorm<<<2, 256, 0, stream>>>(emb, en);
        fb_argmin<<<NROWS / 256, 256, 0, stream>>>(z, emb, en, out, NROWS);
        return;
    }

    char* p = (char*)d_ws;
    i32x4* efA = (i32x4*)p;   p += SZ_EF;
    i32x4* efB = (i32x4*)p;   p += SZ_EF;
    float* en  = (float*)p;   p += SZ_EN;
    float* zn  = (float*)p;   p += SZ_ZN;
    float* emaxp = (float*)p; p += SZ_EMAX;
    int* list = (int*)p;      p += SZ_LIST;
    int* cnt  = (int*)p;

    k1_enorm<<<1, 512, 0, stream>>>(emb, en, emaxp);
    k1_efrag<<<32, 128, 0, stream>>>(emb, efA, efB);
    hipMemsetAsync(cnt, 0, 4, stream);

    k3_fused<<<NROWS / 128, 128, 0, stream>>>(z, efA, efB, en, zn, emaxp, out, list, cnt);
    k4_refine<<<512, 256, 0, stream>>>(z, emb, en, zn, list, cnt, out);
}